// Round 2
// baseline (421.381 us; speedup 1.0000x reference)
//
#include <hip/hip_runtime.h>

#define NN 100000
#define NE 1600000
#define INC 128
#define TE 32
#define OC 128
#define NR 8
#define NBASES 8
#define FT 160
#define KP 168          // padded K stride (bf16 elems) for LDS feat tile
#define KW 160          // unpadded K stride for global Wt
#define TN 32           // nodes per mega block
#define NBKT 3125       // NN/32 dst buckets (exact)
#define NCH 128         // edge chunks
#define EPB 12500       // edges per chunk (128*12500 = NE exactly)
#define CAP 896         // per-bucket edge cap (mean 512, +17 sigma)

typedef float f32x4 __attribute__((ext_vector_type(4)));
typedef float f32x2 __attribute__((ext_vector_type(2)));
typedef __bf16 bf16x8 __attribute__((ext_vector_type(8)));

__device__ __forceinline__ unsigned f2bf1(float f) {
    unsigned u = __float_as_uint(f);
    return (u + 0x7fffu + ((u >> 16) & 1u)) >> 16;   // RNE to bf16
}

__device__ __forceinline__ float bflo(unsigned u) { return __uint_as_float(u << 16); }
__device__ __forceinline__ float bfhi(unsigned u) { return __uint_as_float(u & 0xFFFF0000u); }

// pack two f32 -> bf16 pair (S0 -> low 16, S1 -> high 16), RNE — 1 instr
__device__ __forceinline__ unsigned cvtpk(float a, float b) {
    unsigned r;
    asm("v_cvt_pk_bf16_f32 %0, %1, %2" : "=v"(r) : "v"(a), "v"(b));
    return r;
}

// exclusive block scan over 256 per-thread values (Hillis-Steele in LDS)
__device__ __forceinline__ int bscan_excl(int v, int* tmp) {
    int tid = threadIdx.x;
    tmp[tid] = v; __syncthreads();
#pragma unroll
    for (int d = 1; d < 256; d <<= 1) {
        int t = (tid >= d) ? tmp[tid - d] : 0;
        __syncthreads();
        tmp[tid] += t;
        __syncthreads();
    }
    return tmp[tid] - v;
}

// ---- merged: chunk histograms (blocks 0..NCH-1) + Wt/h precompute (rest) ----
__global__ __launch_bounds__(256) void k_prep(
    const float* __restrict__ x, const int* __restrict__ nt,
    const float* __restrict__ emb, const float* __restrict__ comp,
    const float* __restrict__ bases, const float* __restrict__ rootw,
    const int* __restrict__ ei,
    unsigned short* __restrict__ h, unsigned short* __restrict__ Wt,
    int* __restrict__ ghist) {
    __shared__ int hist[NBKT];
    int tid = threadIdx.x;
    int b = blockIdx.x;
    if (b < NCH) {
        for (int j = tid; j < NBKT; j += 256) hist[j] = 0;
        __syncthreads();
        int e0 = b * EPB;
#pragma unroll
        for (int k = 0; k < 49; k++) {
            int i = k * 256 + tid;
            if (i < EPB) atomicAdd(&hist[ei[NE + e0 + i] >> 5], 1);
        }
        __syncthreads();
        int* g = ghist + (size_t)b * NBKT;
        for (int j = tid; j < NBKT; j += 256) g[j] = hist[j];
        return;
    }
    int idx = (b - NCH) * 256 + tid;
    if (idx < 9 * 128 * KW) {
        int ridx = idx / (128 * KW);
        int rem  = idx % (128 * KW);
        int o = rem / KW;
        int k = rem % KW;
        float v;
        if (ridx < NR) {
            v = 0.f;
#pragma unroll
            for (int bb = 0; bb < NBASES; bb++)
                v += comp[ridx * NBASES + bb] * bases[(bb * FT + k) * OC + o];
        } else {
            v = rootw[k * OC + o];
        }
        Wt[idx] = (unsigned short)f2bf1(v);
    }
    if (idx < NN * 20) {
        int n = idx / 20, c = idx % 20;
        f32x4 v0, v1;
        if (c < 16) {
            const float* p = x + (size_t)n * INC + c * 8;
            v0 = *(const f32x4*)p; v1 = *(const f32x4*)(p + 4);
        } else {
            int tt = nt[n];
            const float* p = emb + tt * TE + (c - 16) * 8;
            v0 = *(const f32x4*)p; v1 = *(const f32x4*)(p + 4);
        }
        uint4 o;
        o.x = f2bf1(v0.x) | (f2bf1(v0.y) << 16);
        o.y = f2bf1(v0.z) | (f2bf1(v0.w) << 16);
        o.z = f2bf1(v1.x) | (f2bf1(v1.y) << 16);
        o.w = f2bf1(v1.z) | (f2bf1(v1.w) << 16);
        *(uint4*)(h + (size_t)n * FT + c * 8) = o;
    }
}

// thread-per-j, loop-over-b: coalesced column sums
__global__ void k_total(const int* __restrict__ ghist, int* __restrict__ total) {
    int j = blockIdx.x * 256 + threadIdx.x;
    if (j >= NBKT) return;
    int s = 0;
#pragma unroll 8
    for (int b = 0; b < NCH; b++) s += ghist[(size_t)b * NBKT + j];
    total[j] = s;
}

__global__ void k_scanTot(const int* __restrict__ total, int* __restrict__ bstart) {
    __shared__ int tmp[256];
    int tid = threadIdx.x, s = 0, i0 = tid * 13;
#pragma unroll
    for (int i = 0; i < 13; i++) { int j = i0 + i; if (j < NBKT) s += total[j]; }
    int run = bscan_excl(s, tmp);
#pragma unroll
    for (int i = 0; i < 13; i++) { int j = i0 + i; if (j < NBKT) { bstart[j] = run; run += total[j]; } }
    if (tid == 0) bstart[NBKT] = NE;
}

// thread-per-j serial prefix over b (coalesced): ghist[b][j] -> absolute chunk start
__global__ void k_offsets(int* __restrict__ ghist, const int* __restrict__ bstart) {
    int j = blockIdx.x * 256 + threadIdx.x;
    if (j >= NBKT) return;
    int run = bstart[j];
#pragma unroll 4
    for (int b = 0; b < NCH; b++) {
        int v = ghist[(size_t)b * NBKT + j];
        ghist[(size_t)b * NBKT + j] = run;
        run += v;
    }
}

// scatter packed entries (src | rel<<17 | dst_local<<20) into bucket-contiguous slots
__global__ __launch_bounds__(256) void k_scatter(const int* __restrict__ ei, const int* __restrict__ et,
                                                 const int* __restrict__ ghist, unsigned* __restrict__ slots) {
    __shared__ int cur[NBKT];
    int tid = threadIdx.x, b = blockIdx.x;
    for (int j = tid; j < NBKT; j += 256) cur[j] = ghist[(size_t)b * NBKT + j];
    __syncthreads();
    int e0 = b * EPB;
#pragma unroll
    for (int k = 0; k < 49; k++) {
        int i = k * 256 + tid;
        if (i < EPB) {
            int e = e0 + i;
            int s = ei[e], d = ei[NE + e], r = et[e];
            int pos = atomicAdd(&cur[d >> 5], 1);
            slots[pos] = (unsigned)s | ((unsigned)r << 17) | ((unsigned)(d & 31) << 20);
        }
    }
}

// ---- fused: in-LDS (rel,node) sort + root GEMM + per-relation (batched stream-mean -> GEMM) + bias + ReLU ----
// LDS = featmem 10752 (overlaid with sort scratch) + sl 3584 + pkl 1024 = 15360 B -> 8 blocks/CU (wave cap)
__global__ __launch_bounds__(256, 8) void k_mega(
    const unsigned short* __restrict__ h, const float* __restrict__ bias,
    const unsigned short* __restrict__ Wt, const int* __restrict__ bstart,
    const unsigned* __restrict__ slots, float* __restrict__ out) {
    __shared__ unsigned short featmem[TN * KP];   // phase 1: sl_in|hist|tmp ; phase 2: feat tile
    __shared__ unsigned sl[CAP];
    __shared__ unsigned pkl[256];

    const int tid = threadIdx.x;
    const int lane = tid & 63;
    const int wave = tid >> 6;
    const int j = blockIdx.x;
    const int n0 = j * TN;

    unsigned* sl_in = reinterpret_cast<unsigned*>(featmem);        // CAP dwords
    int* hist = reinterpret_cast<int*>(featmem) + CAP;             // 256 ints
    int* tmp  = reinterpret_cast<int*>(featmem) + CAP + 256;       // 256 ints

    // ---- phase 1: LDS counting sort by key = rel*32 + dst_local ----
    int s0 = bstart[j];
    int m = bstart[j + 1] - s0; if (m > CAP) m = CAP;
    for (int i = tid; i < m; i += 256) sl_in[i] = slots[s0 + i];
    hist[tid] = 0;
    __syncthreads();
    for (int i = tid; i < m; i += 256) {
        unsigned v = sl_in[i];
        atomicAdd(&hist[((v >> 17) & 7u) * 32u + ((v >> 20) & 31u)], 1);
    }
    __syncthreads();
    int v0 = hist[tid];
    int ex = bscan_excl(v0, tmp);                      // internal syncs cover hist reads
    pkl[tid] = (unsigned)ex | ((unsigned)v0 << 16);
    hist[tid] = ex;                                    // hist becomes scatter cursor
    __syncthreads();
    for (int i = tid; i < m; i += 256) {
        unsigned v = sl_in[i];
        int p = atomicAdd(&hist[((v >> 17) & 7u) * 32u + ((v >> 20) & 31u)], 1);
        sl[p] = v & 0x1FFFFu;                          // only src needed (node from segment bounds)
    }
    __syncthreads();

    // ---- phase 2: featmem becomes the feat tile; root feat straight from h ----
    for (int i = tid; i < TN * 20; i += 256) {
        int nl = i / 20, c = i % 20, n = n0 + nl;
        uint4 v = *reinterpret_cast<const uint4*>(h + (size_t)n * FT + c * 8);
        *reinterpret_cast<uint4*>(&featmem[nl * KP + c * 8]) = v;
    }

    f32x4 acc[4];   // acc[rt*2+ct]
#pragma unroll
    for (int t = 0; t < 4; t++) acc[t] = (f32x4){0.f, 0.f, 0.f, 0.f};

    auto mfma_pass = [&](int ridx) {   // A from LDS feat, B straight from global (L2-resident)
        const unsigned short* fA = featmem + (lane & 15) * KP + ((lane >> 4) * 8);
        const unsigned short* gB = Wt + (size_t)ridx * 128 * KW
                                   + (wave * 32 + (lane & 15)) * KW + ((lane >> 4) * 8);
#pragma unroll
        for (int kc = 0; kc < 5; kc++) {
            bf16x8 a0 = *reinterpret_cast<const bf16x8*>(fA + 0 * 16 * KP + kc * 32);
            bf16x8 a1 = *reinterpret_cast<const bf16x8*>(fA + 1 * 16 * KP + kc * 32);
#pragma unroll
            for (int ct = 0; ct < 2; ct++) {
                bf16x8 b = *reinterpret_cast<const bf16x8*>(gB + ct * 16 * KW + kc * 32);
                acc[0 * 2 + ct] = __builtin_amdgcn_mfma_f32_16x16x32_bf16(a0, b, acc[0 * 2 + ct], 0, 0, 0);
                acc[1 * 2 + ct] = __builtin_amdgcn_mfma_f32_16x16x32_bf16(a1, b, acc[1 * 2 + ct], 0, 0, 0);
            }
        }
    };

    __syncthreads();
    mfma_pass(8);   // root

    // ---- aggregation: group g (16 lanes) streams its 2 nodes' rel-r edges ----
    // lane l owns channels [8l, 8l+8) via dwordx4 at byte 16*l, plus channels 128+2l,129+2l
    // via the tail dword at byte 256+4l (rows are 320 B, 16 B aligned).
    const int g = tid >> 4, l = tid & 15;
    const unsigned* hw = reinterpret_cast<const unsigned*>(h);
    for (int r = 0; r < NR; r++) {
        __syncthreads();   // previous mfma done reading feat
        int b0 = r * 32 + 2 * g;
        unsigned pk1 = pkl[b0 + 1];
        int sbeg = (int)(pkl[b0] & 0xffffu);
        int e1 = (int)(pk1 & 0xffffu);                 // start of node1 == end of node0
        int send = e1 + (int)(pk1 >> 16);
        f32x2 sa[5];
#pragma unroll
        for (int i = 0; i < 5; i++) sa[i] = (f32x2){0.f, 0.f};
        float run = 0.f;
        for (int e = sbeg; e < send; e += 4) {
            uint4 wv[4]; unsigned tv[4];
            // issue all 8 loads (clamped indices: always valid) before consuming any
#pragma unroll
            for (int u = 0; u < 4; u++) {
                int eu = e + u; if (eu >= send) eu = send - 1;
                const unsigned* hp = hw + (size_t)sl[eu] * 80;
                wv[u] = *reinterpret_cast<const uint4*>(hp + 4 * l);
                tv[u] = hp[64 + l];
            }
#pragma unroll
            for (int u = 0; u < 4; u++) {
                if (e + u < send) {
                    sa[0] += (f32x2){bflo(wv[u].x), bfhi(wv[u].x)};
                    sa[1] += (f32x2){bflo(wv[u].y), bfhi(wv[u].y)};
                    sa[2] += (f32x2){bflo(wv[u].z), bfhi(wv[u].z)};
                    sa[3] += (f32x2){bflo(wv[u].w), bfhi(wv[u].w)};
                    sa[4] += (f32x2){bflo(tv[u]), bfhi(tv[u])};
                    run += 1.f;
                    int nx = e + u + 1;
                    if (nx == e1 || nx == send) {      // end of some node's segment
                        int q = (e + u >= e1) ? 1 : 0;
                        float inv = __builtin_amdgcn_rcpf(run);
                        f32x2 m0 = sa[0] * inv, m1 = sa[1] * inv, m2 = sa[2] * inv,
                              m3 = sa[3] * inv, m4 = sa[4] * inv;
                        unsigned* fp = reinterpret_cast<unsigned*>(featmem + (2 * g + q) * KP);
                        uint4 o;
                        o.x = cvtpk(m0.x, m0.y);
                        o.y = cvtpk(m1.x, m1.y);
                        o.z = cvtpk(m2.x, m2.y);
                        o.w = cvtpk(m3.x, m3.y);
                        *reinterpret_cast<uint4*>(fp + 4 * l) = o;
                        fp[64 + l] = cvtpk(m4.x, m4.y);
#pragma unroll
                        for (int i = 0; i < 5; i++) sa[i] = (f32x2){0.f, 0.f};
                        run = 0.f;
                    }
                }
            }
        }
#pragma unroll
        for (int q = 0; q < 2; q++) {                     // zero rows with no rel-r edges
            if ((pkl[b0 + q] >> 16) == 0u) {
                unsigned* fp = reinterpret_cast<unsigned*>(featmem + (2 * g + q) * KP);
                *reinterpret_cast<uint4*>(fp + 4 * l) = (uint4){0u, 0u, 0u, 0u};
                fp[64 + l] = 0u;
            }
        }
        __syncthreads();
        mfma_pass(r);
    }

    // ---- epilogue: bias + ReLU; C/D layout col=lane&15, row=(lane>>4)*4+i per 16x16 tile ----
    const int rq = lane >> 4;
#pragma unroll
    for (int ct = 0; ct < 2; ct++) {
        int col = wave * 32 + ct * 16 + (lane & 15);
        float bv = bias[col];
#pragma unroll
        for (int rt = 0; rt < 2; rt++) {
#pragma unroll
            for (int i = 0; i < 4; i++) {
                int n = n0 + rt * 16 + rq * 4 + i;
                float v = acc[rt * 2 + ct][i] + bv;
                out[(size_t)n * OC + col] = v > 0.f ? v : 0.f;
            }
        }
    }
}

extern "C" void kernel_launch(void* const* d_in, const int* in_sizes, int n_in,
                              void* d_out, int out_size, void* d_ws, size_t ws_size,
                              hipStream_t stream) {
    const float* x     = (const float*)d_in[0];
    const int*   ntype = (const int*)d_in[1];
    const int*   ei    = (const int*)d_in[2];
    const int*   et    = (const int*)d_in[3];
    const float* emb   = (const float*)d_in[4];
    const float* bases = (const float*)d_in[5];
    const float* comp  = (const float*)d_in[6];
    const float* rootw = (const float*)d_in[7];
    const float* bias  = (const float*)d_in[8];
    float* out = (float*)d_out;

    char* ws = (char*)d_ws;
    // 256-aligned layout, ~40.4 MB total:
    unsigned short* Wt     = (unsigned short*)(ws);              // 368,640
    unsigned short* h      = (unsigned short*)(ws + 368640);     // 32,000,000
    int*            ghist  = (int*)(ws + 32368640);              // 1,600,000 B (128 x 3125 ints)
    int*            total  = (int*)(ws + 33968640);              // 12,544
    int*            bstart = (int*)(ws + 33981184);              // 12,544
    unsigned*       slots  = (unsigned*)(ws + 33993728);         // 6,400,000

    k_prep   <<<NCH + 7813, 256, 0, stream>>>(x, ntype, emb, comp, bases, rootw, ei, h, Wt, ghist);
    k_total  <<<13,   256, 0, stream>>>(ghist, total);
    k_scanTot<<<1,    256, 0, stream>>>(total, bstart);
    k_offsets<<<13,   256, 0, stream>>>(ghist, bstart);
    k_scatter<<<NCH,  256, 0, stream>>>(ei, et, ghist, slots);
    k_mega   <<<NBKT, 256, 0, stream>>>(h, bias, Wt, bstart, slots, out);
}

// Round 3
// 349.595 us; speedup vs baseline: 1.2053x; 1.2053x over previous
//
#include <hip/hip_runtime.h>

#define NN 100000
#define NE 1600000
#define INC 128
#define TE 32
#define OC 128
#define NR 8
#define NBASES 8
#define FT 160
#define KP 168          // padded K stride (bf16 elems) for LDS feat tile
#define KW 160          // unpadded K stride for global Wt
#define TN 32           // nodes per mega block
#define NBKT 3125       // NN/32 dst buckets (exact)
#define NCH 128         // edge chunks
#define EPB 12500       // edges per chunk (128*12500 = NE exactly)
#define CAP 896         // per-bucket edge cap (mean 512, +17 sigma)

typedef float f32x4 __attribute__((ext_vector_type(4)));
typedef float f32x2 __attribute__((ext_vector_type(2)));
typedef __bf16 bf16x8 __attribute__((ext_vector_type(8)));

__device__ __forceinline__ unsigned f2bf1(float f) {
    unsigned u = __float_as_uint(f);
    return (u + 0x7fffu + ((u >> 16) & 1u)) >> 16;   // RNE to bf16
}

__device__ __forceinline__ float bflo(unsigned u) { return __uint_as_float(u << 16); }
__device__ __forceinline__ float bfhi(unsigned u) { return __uint_as_float(u & 0xFFFF0000u); }

// pack two f32 -> bf16 pair (S0 -> low 16, S1 -> high 16), RNE — 1 instr
__device__ __forceinline__ unsigned cvtpk(float a, float b) {
    unsigned r;
    asm("v_cvt_pk_bf16_f32 %0, %1, %2" : "=v"(r) : "v"(a), "v"(b));
    return r;
}

// exclusive block scan over 256 per-thread values (Hillis-Steele in LDS)
__device__ __forceinline__ int bscan_excl(int v, int* tmp) {
    int tid = threadIdx.x;
    tmp[tid] = v; __syncthreads();
#pragma unroll
    for (int d = 1; d < 256; d <<= 1) {
        int t = (tid >= d) ? tmp[tid - d] : 0;
        __syncthreads();
        tmp[tid] += t;
        __syncthreads();
    }
    return tmp[tid] - v;
}

// ---- merged: chunk histograms (blocks 0..NCH-1) + Wt/h precompute (rest) ----
__global__ __launch_bounds__(256) void k_prep(
    const float* __restrict__ x, const int* __restrict__ nt,
    const float* __restrict__ emb, const float* __restrict__ comp,
    const float* __restrict__ bases, const float* __restrict__ rootw,
    const int* __restrict__ ei,
    unsigned short* __restrict__ h, unsigned short* __restrict__ Wt,
    int* __restrict__ ghist) {
    __shared__ int hist[NBKT];
    int tid = threadIdx.x;
    int b = blockIdx.x;
    if (b < NCH) {
        for (int j = tid; j < NBKT; j += 256) hist[j] = 0;
        __syncthreads();
        int e0 = b * EPB;
#pragma unroll
        for (int k = 0; k < 49; k++) {
            int i = k * 256 + tid;
            if (i < EPB) atomicAdd(&hist[ei[NE + e0 + i] >> 5], 1);
        }
        __syncthreads();
        int* g = ghist + (size_t)b * NBKT;
        for (int j = tid; j < NBKT; j += 256) g[j] = hist[j];
        return;
    }
    int idx = (b - NCH) * 256 + tid;
    if (idx < 9 * 128 * KW) {
        int ridx = idx / (128 * KW);
        int rem  = idx % (128 * KW);
        int o = rem / KW;
        int k = rem % KW;
        float v;
        if (ridx < NR) {
            v = 0.f;
#pragma unroll
            for (int bb = 0; bb < NBASES; bb++)
                v += comp[ridx * NBASES + bb] * bases[(bb * FT + k) * OC + o];
        } else {
            v = rootw[k * OC + o];
        }
        Wt[idx] = (unsigned short)f2bf1(v);
    }
    if (idx < NN * 20) {
        int n = idx / 20, c = idx % 20;
        f32x4 v0, v1;
        if (c < 16) {
            const float* p = x + (size_t)n * INC + c * 8;
            v0 = *(const f32x4*)p; v1 = *(const f32x4*)(p + 4);
        } else {
            int tt = nt[n];
            const float* p = emb + tt * TE + (c - 16) * 8;
            v0 = *(const f32x4*)p; v1 = *(const f32x4*)(p + 4);
        }
        uint4 o;
        o.x = f2bf1(v0.x) | (f2bf1(v0.y) << 16);
        o.y = f2bf1(v0.z) | (f2bf1(v0.w) << 16);
        o.z = f2bf1(v1.x) | (f2bf1(v1.y) << 16);
        o.w = f2bf1(v1.z) | (f2bf1(v1.w) << 16);
        *(uint4*)(h + (size_t)n * FT + c * 8) = o;
    }
}

// thread-per-j, loop-over-b: coalesced column sums
__global__ void k_total(const int* __restrict__ ghist, int* __restrict__ total) {
    int j = blockIdx.x * 256 + threadIdx.x;
    if (j >= NBKT) return;
    int s = 0;
#pragma unroll 8
    for (int b = 0; b < NCH; b++) s += ghist[(size_t)b * NBKT + j];
    total[j] = s;
}

__global__ void k_scanTot(const int* __restrict__ total, int* __restrict__ bstart) {
    __shared__ int tmp[256];
    int tid = threadIdx.x, s = 0, i0 = tid * 13;
#pragma unroll
    for (int i = 0; i < 13; i++) { int j = i0 + i; if (j < NBKT) s += total[j]; }
    int run = bscan_excl(s, tmp);
#pragma unroll
    for (int i = 0; i < 13; i++) { int j = i0 + i; if (j < NBKT) { bstart[j] = run; run += total[j]; } }
    if (tid == 0) bstart[NBKT] = NE;
}

// thread-per-j serial prefix over b (coalesced): ghist[b][j] -> absolute chunk start
__global__ void k_offsets(int* __restrict__ ghist, const int* __restrict__ bstart) {
    int j = blockIdx.x * 256 + threadIdx.x;
    if (j >= NBKT) return;
    int run = bstart[j];
#pragma unroll 4
    for (int b = 0; b < NCH; b++) {
        int v = ghist[(size_t)b * NBKT + j];
        ghist[(size_t)b * NBKT + j] = run;
        run += v;
    }
}

// scatter packed entries (src | rel<<17 | dst_local<<20) into bucket-contiguous slots
__global__ __launch_bounds__(256) void k_scatter(const int* __restrict__ ei, const int* __restrict__ et,
                                                 const int* __restrict__ ghist, unsigned* __restrict__ slots) {
    __shared__ int cur[NBKT];
    int tid = threadIdx.x, b = blockIdx.x;
    for (int j = tid; j < NBKT; j += 256) cur[j] = ghist[(size_t)b * NBKT + j];
    __syncthreads();
    int e0 = b * EPB;
#pragma unroll
    for (int k = 0; k < 49; k++) {
        int i = k * 256 + tid;
        if (i < EPB) {
            int e = e0 + i;
            int s = ei[e], d = ei[NE + e], r = et[e];
            int pos = atomicAdd(&cur[d >> 5], 1);
            slots[pos] = (unsigned)s | ((unsigned)r << 17) | ((unsigned)(d & 31) << 20);
        }
    }
}

// ---- fused: in-LDS (rel,node) sort + root GEMM + per-relation (batched stream-mean -> GEMM) + bias + ReLU ----
// LDS = featmem 10752 (overlaid with sort scratch) + sl 3584 + pkl 1024 = 15360 B
// bound (256,6): VGPR cap ~84/wave -> no scratch spill (round-2 lesson: (256,8) spilled the
// batch-4 gather pipeline, +230 MB scratch writes); 6 blocks/CU = 75% occupancy ceiling.
__global__ __launch_bounds__(256, 6) void k_mega(
    const unsigned short* __restrict__ h, const float* __restrict__ bias,
    const unsigned short* __restrict__ Wt, const int* __restrict__ bstart,
    const unsigned* __restrict__ slots, float* __restrict__ out) {
    __shared__ unsigned short featmem[TN * KP];   // phase 1: sl_in|hist|tmp ; phase 2: feat tile
    __shared__ unsigned sl[CAP];
    __shared__ unsigned pkl[256];

    const int tid = threadIdx.x;
    const int lane = tid & 63;
    const int wave = tid >> 6;
    const int j = blockIdx.x;
    const int n0 = j * TN;

    unsigned* sl_in = reinterpret_cast<unsigned*>(featmem);        // CAP dwords
    int* hist = reinterpret_cast<int*>(featmem) + CAP;             // 256 ints
    int* tmp  = reinterpret_cast<int*>(featmem) + CAP + 256;       // 256 ints

    // ---- phase 1: LDS counting sort by key = rel*32 + dst_local ----
    int s0 = bstart[j];
    int m = bstart[j + 1] - s0; if (m > CAP) m = CAP;
    for (int i = tid; i < m; i += 256) sl_in[i] = slots[s0 + i];
    hist[tid] = 0;
    __syncthreads();
    for (int i = tid; i < m; i += 256) {
        unsigned v = sl_in[i];
        atomicAdd(&hist[((v >> 17) & 7u) * 32u + ((v >> 20) & 31u)], 1);
    }
    __syncthreads();
    int v0 = hist[tid];
    int ex = bscan_excl(v0, tmp);                      // internal syncs cover hist reads
    pkl[tid] = (unsigned)ex | ((unsigned)v0 << 16);
    hist[tid] = ex;                                    // hist becomes scatter cursor
    __syncthreads();
    for (int i = tid; i < m; i += 256) {
        unsigned v = sl_in[i];
        int p = atomicAdd(&hist[((v >> 17) & 7u) * 32u + ((v >> 20) & 31u)], 1);
        sl[p] = v & 0x1FFFFu;                          // only src needed (node from segment bounds)
    }
    __syncthreads();

    // ---- phase 2: featmem becomes the feat tile; root feat straight from h ----
    for (int i = tid; i < TN * 20; i += 256) {
        int nl = i / 20, c = i % 20, n = n0 + nl;
        uint4 v = *reinterpret_cast<const uint4*>(h + (size_t)n * FT + c * 8);
        *reinterpret_cast<uint4*>(&featmem[nl * KP + c * 8]) = v;
    }

    f32x4 acc[4];   // acc[rt*2+ct]
#pragma unroll
    for (int t = 0; t < 4; t++) acc[t] = (f32x4){0.f, 0.f, 0.f, 0.f};

    auto mfma_pass = [&](int ridx) {   // A from LDS feat, B straight from global (L2-resident)
        const unsigned short* fA = featmem + (lane & 15) * KP + ((lane >> 4) * 8);
        const unsigned short* gB = Wt + (size_t)ridx * 128 * KW
                                   + (wave * 32 + (lane & 15)) * KW + ((lane >> 4) * 8);
#pragma unroll
        for (int kc = 0; kc < 5; kc++) {
            bf16x8 a0 = *reinterpret_cast<const bf16x8*>(fA + 0 * 16 * KP + kc * 32);
            bf16x8 a1 = *reinterpret_cast<const bf16x8*>(fA + 1 * 16 * KP + kc * 32);
#pragma unroll
            for (int ct = 0; ct < 2; ct++) {
                bf16x8 b = *reinterpret_cast<const bf16x8*>(gB + ct * 16 * KW + kc * 32);
                acc[0 * 2 + ct] = __builtin_amdgcn_mfma_f32_16x16x32_bf16(a0, b, acc[0 * 2 + ct], 0, 0, 0);
                acc[1 * 2 + ct] = __builtin_amdgcn_mfma_f32_16x16x32_bf16(a1, b, acc[1 * 2 + ct], 0, 0, 0);
            }
        }
    };

    __syncthreads();
    mfma_pass(8);   // root

    // ---- aggregation: group g (16 lanes) streams its 2 nodes' rel-r edges ----
    // lane l owns channels [8l, 8l+8) via dwordx4 at byte 16*l, plus channels 128+2l,129+2l
    // via the tail dword at byte 256+4l (rows are 320 B, 16 B aligned).
    const int g = tid >> 4, l = tid & 15;
    const unsigned* hw = reinterpret_cast<const unsigned*>(h);
    for (int r = 0; r < NR; r++) {
        __syncthreads();   // previous mfma done reading feat
        int b0 = r * 32 + 2 * g;
        unsigned pk1 = pkl[b0 + 1];
        int sbeg = (int)(pkl[b0] & 0xffffu);
        int e1 = (int)(pk1 & 0xffffu);                 // start of node1 == end of node0
        int send = e1 + (int)(pk1 >> 16);
        f32x2 sa[5];
#pragma unroll
        for (int i = 0; i < 5; i++) sa[i] = (f32x2){0.f, 0.f};
        float run = 0.f;
        for (int e = sbeg; e < send; e += 4) {
            uint4 wv[4]; unsigned tv[4];
            // issue all 8 loads (clamped indices: always valid) before consuming any
#pragma unroll
            for (int u = 0; u < 4; u++) {
                int eu = e + u; if (eu >= send) eu = send - 1;
                const unsigned* hp = hw + (size_t)sl[eu] * 80;
                wv[u] = *reinterpret_cast<const uint4*>(hp + 4 * l);
                tv[u] = hp[64 + l];
            }
#pragma unroll
            for (int u = 0; u < 4; u++) {
                if (e + u < send) {
                    sa[0] += (f32x2){bflo(wv[u].x), bfhi(wv[u].x)};
                    sa[1] += (f32x2){bflo(wv[u].y), bfhi(wv[u].y)};
                    sa[2] += (f32x2){bflo(wv[u].z), bfhi(wv[u].z)};
                    sa[3] += (f32x2){bflo(wv[u].w), bfhi(wv[u].w)};
                    sa[4] += (f32x2){bflo(tv[u]), bfhi(tv[u])};
                    run += 1.f;
                    int nx = e + u + 1;
                    if (nx == e1 || nx == send) {      // end of some node's segment
                        int q = (e + u >= e1) ? 1 : 0;
                        float inv = __builtin_amdgcn_rcpf(run);
                        f32x2 m0 = sa[0] * inv, m1 = sa[1] * inv, m2 = sa[2] * inv,
                              m3 = sa[3] * inv, m4 = sa[4] * inv;
                        unsigned* fp = reinterpret_cast<unsigned*>(featmem + (2 * g + q) * KP);
                        uint4 o;
                        o.x = cvtpk(m0.x, m0.y);
                        o.y = cvtpk(m1.x, m1.y);
                        o.z = cvtpk(m2.x, m2.y);
                        o.w = cvtpk(m3.x, m3.y);
                        *reinterpret_cast<uint4*>(fp + 4 * l) = o;
                        fp[64 + l] = cvtpk(m4.x, m4.y);
#pragma unroll
                        for (int i = 0; i < 5; i++) sa[i] = (f32x2){0.f, 0.f};
                        run = 0.f;
                    }
                }
            }
        }
#pragma unroll
        for (int q = 0; q < 2; q++) {                     // zero rows with no rel-r edges
            if ((pkl[b0 + q] >> 16) == 0u) {
                unsigned* fp = reinterpret_cast<unsigned*>(featmem + (2 * g + q) * KP);
                *reinterpret_cast<uint4*>(fp + 4 * l) = (uint4){0u, 0u, 0u, 0u};
                fp[64 + l] = 0u;
            }
        }
        __syncthreads();
        mfma_pass(r);
    }

    // ---- epilogue: bias + ReLU; C/D layout col=lane&15, row=(lane>>4)*4+i per 16x16 tile ----
    const int rq = lane >> 4;
#pragma unroll
    for (int ct = 0; ct < 2; ct++) {
        int col = wave * 32 + ct * 16 + (lane & 15);
        float bv = bias[col];
#pragma unroll
        for (int rt = 0; rt < 2; rt++) {
#pragma unroll
            for (int i = 0; i < 4; i++) {
                int n = n0 + rt * 16 + rq * 4 + i;
                float v = acc[rt * 2 + ct][i] + bv;
                out[(size_t)n * OC + col] = v > 0.f ? v : 0.f;
            }
        }
    }
}

extern "C" void kernel_launch(void* const* d_in, const int* in_sizes, int n_in,
                              void* d_out, int out_size, void* d_ws, size_t ws_size,
                              hipStream_t stream) {
    const float* x     = (const float*)d_in[0];
    const int*   ntype = (const int*)d_in[1];
    const int*   ei    = (const int*)d_in[2];
    const int*   et    = (const int*)d_in[3];
    const float* emb   = (const float*)d_in[4];
    const float* bases = (const float*)d_in[5];
    const float* comp  = (const float*)d_in[6];
    const float* rootw = (const float*)d_in[7];
    const float* bias  = (const float*)d_in[8];
    float* out = (float*)d_out;

    char* ws = (char*)d_ws;
    // 256-aligned layout, ~40.4 MB total:
    unsigned short* Wt     = (unsigned short*)(ws);              // 368,640
    unsigned short* h      = (unsigned short*)(ws + 368640);     // 32,000,000
    int*            ghist  = (int*)(ws + 32368640);              // 1,600,000 B (128 x 3125 ints)
    int*            total  = (int*)(ws + 33968640);              // 12,544
    int*            bstart = (int*)(ws + 33981184);              // 12,544
    unsigned*       slots  = (unsigned*)(ws + 33993728);         // 6,400,000

    k_prep   <<<NCH + 7813, 256, 0, stream>>>(x, ntype, emb, comp, bases, rootw, ei, h, Wt, ghist);
    k_total  <<<13,   256, 0, stream>>>(ghist, total);
    k_scanTot<<<1,    256, 0, stream>>>(total, bstart);
    k_offsets<<<13,   256, 0, stream>>>(ghist, bstart);
    k_scatter<<<NCH,  256, 0, stream>>>(ei, et, ghist, slots);
    k_mega   <<<NBKT, 256, 0, stream>>>(h, bias, Wt, bstart, slots, out);
}